// Round 1
// baseline (27.168 us; speedup 1.0000x reference)
//
#include <hip/hip_runtime.h>

#define KDIM 2048
#define BDIM 32
#define W_RESOURCE 100.0f
#define CHUNKS 8   // blocks per batch; each block handles 256 consecutive i's

__global__ __launch_bounds__(256) void alloc_kernel(const float* __restrict__ values,
                                                    const float* __restrict__ weights,
                                                    float* __restrict__ out) {
    __shared__ float sv[KDIM];
    __shared__ float sw[KDIM];

    const int b     = blockIdx.x >> 3;   // blockIdx.x / CHUNKS
    const int chunk = blockIdx.x & 7;    // blockIdx.x % CHUNKS
    const int tid   = threadIdx.x;

    // Cooperative staging: batch row of v and w into LDS, float4-vectorized.
    const float4* v4 = reinterpret_cast<const float4*>(values + (size_t)b * KDIM);
    const float4* w4 = reinterpret_cast<const float4*>(weights + (size_t)b * KDIM);
    float4* sv4 = reinterpret_cast<float4*>(sv);
    float4* sw4 = reinterpret_cast<float4*>(sw);
    #pragma unroll
    for (int t = tid; t < KDIM / 4; t += 256) {
        sv4[t] = v4[t];
        sw4[t] = w4[t];
    }
    __syncthreads();

    const int i  = chunk * 256 + tid;
    const float vi = sv[i];

    float acc = 0.0f;
    #pragma unroll 4
    for (int j4 = 0; j4 < KDIM / 4; ++j4) {
        // Same address across all lanes -> LDS broadcast (conflict-free).
        float4 vj = sv4[j4];
        float4 wj = sw4[j4];
        acc += (vj.x >= vi) ? wj.x : 0.0f;
        acc += (vj.y >= vi) ? wj.y : 0.0f;
        acc += (vj.z >= vi) ? wj.z : 0.0f;
        acc += (vj.w >= vi) ? wj.w : 0.0f;
    }

    out[(size_t)b * KDIM + i] = (W_RESOURCE - acc >= 0.0f) ? sw[i] : 0.0f;
}

extern "C" void kernel_launch(void* const* d_in, const int* in_sizes, int n_in,
                              void* d_out, int out_size, void* d_ws, size_t ws_size,
                              hipStream_t stream) {
    const float* values  = (const float*)d_in[0];
    const float* weights = (const float*)d_in[1];
    float* out = (float*)d_out;

    dim3 grid(BDIM * CHUNKS);  // 256 blocks
    dim3 block(256);
    alloc_kernel<<<grid, block, 0, stream>>>(values, weights, out);
}

// Round 2
// 16.138 us; speedup vs baseline: 1.6835x; 1.6835x over previous
//
#include <hip/hip_runtime.h>

#define KDIM 2048
#define BDIM 32
#define W_RESOURCE 100.0f
#define CHUNKS 8    // blocks per batch; each block handles 256 consecutive i's
#define SLICES 4    // j-dimension slices per block (threads 1024 = 256 i x 4 slices)

__global__ __launch_bounds__(1024) void alloc_kernel(const float* __restrict__ values,
                                                     const float* __restrict__ weights,
                                                     float* __restrict__ out) {
    __shared__ float sv[KDIM];
    __shared__ float sw[KDIM];
    __shared__ float part[SLICES][256];

    const int b     = blockIdx.x >> 3;   // blockIdx.x / CHUNKS
    const int chunk = blockIdx.x & 7;    // blockIdx.x % CHUNKS
    const int tid   = threadIdx.x;       // 0..1023

    // Cooperative staging: 1024 float4 loads total, exactly one per thread.
    const float4* v4 = reinterpret_cast<const float4*>(values + (size_t)b * KDIM);
    const float4* w4 = reinterpret_cast<const float4*>(weights + (size_t)b * KDIM);
    float4* sv4 = reinterpret_cast<float4*>(sv);
    float4* sw4 = reinterpret_cast<float4*>(sw);
    if (tid < KDIM / 4) {
        sv4[tid] = v4[tid];
    } else {
        sw4[tid - KDIM / 4] = w4[tid - KDIM / 4];
    }
    __syncthreads();

    const int i_local = tid & 255;       // which i within the chunk
    const int slice   = tid >> 8;        // which j-slice (0..3)
    const int i       = chunk * 256 + i_local;
    const float vi    = sv[i];

    // Each slice covers KDIM/4/SLICES = 128 float4 groups.
    const int j4_begin = slice * (KDIM / 4 / SLICES);
    const int j4_end   = j4_begin + (KDIM / 4 / SLICES);

    float acc = 0.0f;
    #pragma unroll 4
    for (int j4 = j4_begin; j4 < j4_end; ++j4) {
        // Same address across all lanes of a wave -> LDS broadcast.
        float4 vj = sv4[j4];
        float4 wj = sw4[j4];
        acc += (vj.x >= vi) ? wj.x : 0.0f;
        acc += (vj.y >= vi) ? wj.y : 0.0f;
        acc += (vj.z >= vi) ? wj.z : 0.0f;
        acc += (vj.w >= vi) ? wj.w : 0.0f;
    }

    part[slice][i_local] = acc;
    __syncthreads();

    if (slice == 0) {
        float load = part[0][i_local] + part[1][i_local] + part[2][i_local] + part[3][i_local];
        out[(size_t)b * KDIM + i] = (W_RESOURCE - load >= 0.0f) ? sw[i] : 0.0f;
    }
}

extern "C" void kernel_launch(void* const* d_in, const int* in_sizes, int n_in,
                              void* d_out, int out_size, void* d_ws, size_t ws_size,
                              hipStream_t stream) {
    const float* values  = (const float*)d_in[0];
    const float* weights = (const float*)d_in[1];
    float* out = (float*)d_out;

    dim3 grid(BDIM * CHUNKS);  // 256 blocks, one per CU
    dim3 block(1024);          // 256 i x 4 j-slices = 16 waves/block
    alloc_kernel<<<grid, block, 0, stream>>>(values, weights, out);
}

// Round 3
// 14.597 us; speedup vs baseline: 1.8612x; 1.1056x over previous
//
#include <hip/hip_runtime.h>

#define KDIM 2048
#define BDIM 32
#define W_RESOURCE 100.0f
#define CHUNKS 8     // i-chunks per batch; each block handles 256 consecutive i's
#define SLICES 16    // j-slices = waves per block (wave-uniform slice -> LDS broadcast)
#define G 4          // i's per thread: each LDS read pair feeds 4 accumulators

__global__ __launch_bounds__(1024) void alloc_kernel(const float* __restrict__ values,
                                                     const float* __restrict__ weights,
                                                     float* __restrict__ out) {
    __shared__ float sv[KDIM];
    __shared__ float sw[KDIM];
    __shared__ float part[SLICES][256];

    const int b     = blockIdx.x >> 3;   // batch
    const int chunk = blockIdx.x & 7;    // which 256-wide i chunk
    const int tid   = threadIdx.x;       // 0..1023

    // Stage full batch row of v and w: 1024 float4 loads, one per thread.
    const float4* v4 = reinterpret_cast<const float4*>(values + (size_t)b * KDIM);
    const float4* w4 = reinterpret_cast<const float4*>(weights + (size_t)b * KDIM);
    float4* sv4 = reinterpret_cast<float4*>(sv);
    float4* sw4 = reinterpret_cast<float4*>(sw);
    if (tid < KDIM / 4) {
        sv4[tid] = v4[tid];
    } else {
        sw4[tid - KDIM / 4] = w4[tid - KDIM / 4];
    }
    __syncthreads();

    const int lane  = tid & 63;
    const int slice = tid >> 6;          // == wave id: wave-uniform -> broadcast reads

    // Each thread owns G=4 i's: i_local = g*64 + lane (g = 0..3)
    float vi[G], acc[G];
    #pragma unroll
    for (int g = 0; g < G; ++g) {
        vi[g]  = sv[chunk * 256 + g * 64 + lane];
        acc[g] = 0.0f;
    }

    // Slice covers KDIM/4/SLICES = 32 float4 groups.
    const int j4_begin = slice * (KDIM / 4 / SLICES);

    #pragma unroll
    for (int it = 0; it < KDIM / 4 / SLICES; ++it) {
        const int j4 = j4_begin + it;
        float4 vj = sv4[j4];             // wave-uniform address -> LDS broadcast
        float4 wj = sw4[j4];
        #pragma unroll
        for (int g = 0; g < G; ++g) {
            float a = acc[g];
            a += (vj.x >= vi[g]) ? wj.x : 0.0f;
            a += (vj.y >= vi[g]) ? wj.y : 0.0f;
            a += (vj.z >= vi[g]) ? wj.z : 0.0f;
            a += (vj.w >= vi[g]) ? wj.w : 0.0f;
            acc[g] = a;
        }
    }

    #pragma unroll
    for (int g = 0; g < G; ++g)
        part[slice][g * 64 + lane] = acc[g];
    __syncthreads();

    // Reduce 16 partials per i; threads 0..255 each own one i.
    if (tid < 256) {
        float load = 0.0f;
        #pragma unroll
        for (int s = 0; s < SLICES; ++s)
            load += part[s][tid];
        out[(size_t)b * KDIM + chunk * 256 + tid] =
            (W_RESOURCE - load >= 0.0f) ? sw[chunk * 256 + tid] : 0.0f;
    }
}

extern "C" void kernel_launch(void* const* d_in, const int* in_sizes, int n_in,
                              void* d_out, int out_size, void* d_ws, size_t ws_size,
                              hipStream_t stream) {
    const float* values  = (const float*)d_in[0];
    const float* weights = (const float*)d_in[1];
    float* out = (float*)d_out;

    dim3 grid(BDIM * CHUNKS);  // 256 blocks, 1 per CU
    dim3 block(1024);          // 16 waves = 16 j-slices, 4 waves/SIMD
    alloc_kernel<<<grid, block, 0, stream>>>(values, weights, out);
}